// Round 3
// baseline (1674.592 us; speedup 1.0000x reference)
//
#include <hip/hip_runtime.h>

// ---------------------------------------------------------------------------
// FutureCameraHead on MI355X (gfx950)
// Trunk: each ResConvBlock (3 x Linear(512,512)+ReLU + residual) fused into a
// single kernel. 64-row x 512-col tile in LDS (XOR-swizzled); weights stream
// from a fragment-linear packed buffer straight to registers (no K-loop
// barriers -> compiler pipelines vmcnt). mfma_f32_32x32x16_bf16, operands
// swapped (A=W, B=X) so the epilogue packs 4 consecutive cols -> ds_write_b64.
// Tail (rows<=192) in fp32. 3x3 SVD orthogonalize via fp64 Jacobi + Kabsch.
// ---------------------------------------------------------------------------

typedef unsigned short u16;
typedef __attribute__((ext_vector_type(8))) short short8;    // 8 x bf16 (4 VGPRs)
typedef __attribute__((ext_vector_type(16))) float f32x16;   // 32x32 MFMA acc

constexpr int  DDIM   = 512;
constexpr long R_ROWS = 96L * 1369L;   // 131424 (BN * hw)
constexpr long R_PAD  = 2054L * 64L;   // 131456 buffer rows (64-row tiles, exact)

__device__ __forceinline__ u16 f2b(float f) {  // fp32 -> bf16 RNE
  union { float f; unsigned u; } x; x.f = f;
  unsigned r = (x.u + 0x7FFFu + ((x.u >> 16) & 1u)) >> 16;
  return (u16)r;
}
__device__ __forceinline__ float b2f(u16 b) {
  union { unsigned u; float f; } x; x.u = ((unsigned)b) << 16;
  return x.f;
}

// --- feat fp32 -> bf16 padded buffer (pad rows zeroed) ----------------------
__global__ void convert_feat_k(const float* __restrict__ in, u16* __restrict__ out) {
  long i4 = ((long)blockIdx.x * 256 + threadIdx.x) * 4;
  if (i4 >= R_PAD * DDIM) return;
  ushort4 o;
  if (i4 < R_ROWS * DDIM) {
    float4 v = *(const float4*)(in + i4);
    o.x = f2b(v.x); o.y = f2b(v.y); o.z = f2b(v.z); o.w = f2b(v.w);
  } else {
    o.x = 0; o.y = 0; o.z = 0; o.w = 0;
  }
  *(ushort4*)(out + i4) = o;
}

// --- W_res [6][K=512][N=512] fp32 -> fragment-linear packed bf16 ------------
// Wp[g][ks][q][n][j] = W[g][ks*16+q*8+j][n]   (ks=k-slice of 16, q=lane>>5)
// A 32x32x16 A-fragment load is then one coalesced dwordx4 per lane.
__global__ void pack_w_k(const float* __restrict__ W, u16* __restrict__ Wp) {
  int tid = blockIdx.x * 256 + threadIdx.x;
  if (tid >= 6 * 262144) return;
  int g  = tid >> 18, t2 = tid & 262143;
  int ks = t2 >> 13, t3 = t2 & 8191;
  int q  = t3 >> 12, t4 = t3 & 4095;
  int n  = t4 >> 3,  j  = t4 & 7;
  int k  = ks * 16 + q * 8 + j;
  Wp[tid] = f2b(W[(long)g * 262144 + (long)k * 512 + n]);
}

// --- fused ResConvBlock: Xg[rows] = Xg + relu(L3(relu(L2(relu(L1(Xg)))))) ---
// Block: 256 thr (4 waves), tile = 64 rows x 512 cols. Yb (LDS, swizzled)
// holds the current activation tile; weights stream from Wp (L2-hot).
// MFMA roles: A=W (m=out-col), B=X (n=row)  =>  D[m][n] = Y^T fragment.
// C/D: n = lane&31 (X-row), m = (reg&3) + 8*(reg>>2) + 4*(lane>>5).
__global__ __launch_bounds__(256, 2)
void fused_res_k(u16* __restrict__ Xg, const u16* __restrict__ Wp,
                 const float* __restrict__ bres) {
  __shared__ u16 Yb[64 * 512];   // 64 KB, chunk(r,k8) at r*64 + (k8 ^ r)
  const int tid = threadIdx.x;
  const int lane = tid & 63;
  const int wvC  = tid >> 6;     // wave = col group: cols [wvC*128, +128)
  const int l31  = lane & 31;
  const int q    = lane >> 5;
  const long rowBase = (long)blockIdx.x * 64;

  // ---- stage 64x512 input tile into swizzled Yb (global_load_lds x16B) ----
#pragma unroll
  for (int i = 0; i < 16; ++i) {
    int L = i * 256 + tid;           // LDS chunk 0..4095
    int r = L >> 6, cS = L & 63;
    int c = cS ^ r;                  // global k8 held by this LDS slot
    const u16* ga = Xg + (rowBase + r) * DDIM + c * 8;
    __builtin_amdgcn_global_load_lds(
        (const __attribute__((address_space(1))) void*)ga,
        (__attribute__((address_space(3))) void*)&Yb[L * 8], 16, 0, 0);
  }
  __syncthreads();

  for (int l = 0; l < 3; ++l) {
    const u16* wl = Wp + (long)l * 262144;
    const float* bias = bres + l * 512;

    f32x16 acc[4][2];
#pragma unroll
    for (int mi = 0; mi < 4; ++mi)
#pragma unroll
      for (int nb = 0; nb < 2; ++nb)
#pragma unroll
        for (int e = 0; e < 16; ++e) acc[mi][nb][e] = 0.f;

    // ---- barrier-free K loop: W from global (coalesced), X from LDS ----
#pragma unroll 4
    for (int ks = 0; ks < 32; ++ks) {
      const int k8 = ks * 2 + q;
      const u16* wk = wl + ((long)(k8) * 512 + wvC * 128 + l31) * 8;
      short8 wf[4];
#pragma unroll
      for (int mi = 0; mi < 4; ++mi)
        wf[mi] = *(const short8*)(wk + mi * 32 * 8);
      short8 xf[2];
#pragma unroll
      for (int nb = 0; nb < 2; ++nb) {
        int r = nb * 32 + l31;
        xf[nb] = *(const short8*)&Yb[(r * 64 + (k8 ^ r)) * 8];
      }
#pragma unroll
      for (int mi = 0; mi < 4; ++mi)
#pragma unroll
        for (int nb = 0; nb < 2; ++nb)
          acc[mi][nb] = __builtin_amdgcn_mfma_f32_32x32x16_bf16(
              wf[mi], xf[nb], acc[mi][nb], 0, 0, 0);
    }
    __syncthreads();   // all Yb reads done before overwrite / next phase

    if (l < 2) {
      // ---- epilogue -> Yb (bf16, swizzled), 4-col packs via b64 writes ----
#pragma unroll
      for (int mi = 0; mi < 4; ++mi) {
#pragma unroll
        for (int j2 = 0; j2 < 4; ++j2) {
          int n0 = wvC * 128 + mi * 32 + 4 * q + 8 * j2;
          float4 bv = *(const float4*)(bias + n0);
#pragma unroll
          for (int nb = 0; nb < 2; ++nb) {
            int r = nb * 32 + l31;
            ushort4 pk;
            pk.x = f2b(fmaxf(acc[mi][nb][4 * j2 + 0] + bv.x, 0.f));
            pk.y = f2b(fmaxf(acc[mi][nb][4 * j2 + 1] + bv.y, 0.f));
            pk.z = f2b(fmaxf(acc[mi][nb][4 * j2 + 2] + bv.z, 0.f));
            pk.w = f2b(fmaxf(acc[mi][nb][4 * j2 + 3] + bv.w, 0.f));
            *(ushort4*)&Yb[(r * 64 + ((n0 >> 3) ^ r)) * 8 + (n0 & 7)] = pk;
          }
        }
      }
      __syncthreads();
    } else {
      // ---- final epilogue: + residual from Xg, write back to Xg ----
#pragma unroll
      for (int mi = 0; mi < 4; ++mi) {
#pragma unroll
        for (int j2 = 0; j2 < 4; ++j2) {
          int n0 = wvC * 128 + mi * 32 + 4 * q + 8 * j2;
          float4 bv = *(const float4*)(bias + n0);
#pragma unroll
          for (int nb = 0; nb < 2; ++nb) {
            int r = nb * 32 + l31;
            u16* gp = Xg + (rowBase + r) * DDIM + n0;
            ushort4 xv = *(const ushort4*)gp;
            ushort4 pk;
            pk.x = f2b(fmaxf(acc[mi][nb][4 * j2 + 0] + bv.x, 0.f) + b2f(xv.x));
            pk.y = f2b(fmaxf(acc[mi][nb][4 * j2 + 1] + bv.y, 0.f) + b2f(xv.y));
            pk.z = f2b(fmaxf(acc[mi][nb][4 * j2 + 2] + bv.z, 0.f) + b2f(xv.z));
            pk.w = f2b(fmaxf(acc[mi][nb][4 * j2 + 3] + bv.w, 0.f) + b2f(xv.w));
            *(ushort4*)gp = pk;
          }
        }
      }
    }
  }
}

// --- pooling: pooled[bn][d] = mean_p feat[bn*1369+p][d] ---------------------
__global__ void zero_k(float* p, int n) {
  int i = blockIdx.x * 256 + threadIdx.x;
  if (i < n) p[i] = 0.f;
}

__global__ void pool_k(const u16* __restrict__ feat, float* __restrict__ pooled) {
  int bn = blockIdx.x, ch = blockIdx.y, d = threadIdx.x;  // block 512
  int p0 = ch * 172, p1 = p0 + 172;
  if (p1 > 1369) p1 = 1369;
  float s = 0.f;
  long base = ((long)bn * 1369 + p0) * DDIM + d;
  for (int p = p0; p < p1; ++p) { s += b2f(feat[base]); base += DDIM; }
  atomicAdd(&pooled[bn * DDIM + d], s * (1.0f / 1369.0f));
}

__global__ void gctx_k(const float* __restrict__ pooled, float* __restrict__ gctx) {
  int i = blockIdx.x * 256 + threadIdx.x;  // 32*512
  if (i >= 32 * DDIM) return;
  int b = i >> 9, d = i & 511;
  const float* p = pooled + (long)b * 3 * DDIM + d;
  gctx[i] = (p[0] + p[DDIM] + p[2 * DDIM]) * (1.0f / 3.0f);
}

// --- small fp32 linear: out[r][n] = act(in[r,:] @ W[:,n] + b[n]) ------------
template <bool RELU>
__global__ void lin_k(const float* __restrict__ in, const float* __restrict__ W,
                      const float* __restrict__ bias, float* __restrict__ out,
                      int K, int N) {
  int n = blockIdx.x * 256 + threadIdx.x;
  int r = blockIdx.y;
  if (n >= N) return;
  float acc = bias[n];
  const float* xi = in + (long)r * K;
#pragma unroll 8
  for (int k = 0; k < K; ++k) acc = fmaf(xi[k], W[(long)k * N + n], acc);
  if (RELU) acc = fmaxf(acc, 0.f);
  out[(long)r * N + n] = acc;
}

// --- pose head: 12 dots + fp64 Jacobi SVD orthogonalize + 4x4 assemble ------
__global__ void pose_k(const float* __restrict__ h,
                       const float* __restrict__ Wt, const float* __restrict__ bt,
                       const float* __restrict__ Wr, const float* __restrict__ br,
                       float* __restrict__ out) {
  int row = blockIdx.x;
  int lane = threadIdx.x;  // 64
  const float* hr = h + (long)row * DDIM;
  float part[12];
#pragma unroll
  for (int c = 0; c < 12; ++c) {
    float acc = 0.f;
    for (int k = lane; k < DDIM; k += 64) {
      float wvv = (c < 3) ? Wt[k * 3 + c] : Wr[k * 9 + (c - 3)];
      acc += hr[k] * wvv;
    }
#pragma unroll
    for (int off = 32; off > 0; off >>= 1) acc += __shfl_down(acc, off);
    part[c] = acc;
  }
  if (lane != 0) return;

  double t3[3];
  for (int i = 0; i < 3; ++i) t3[i] = (double)part[i] + (double)bt[i];
  double m[3][3];
  for (int i = 0; i < 3; ++i)
    for (int j = 0; j < 3; ++j) m[i][j] = (double)part[3 + i * 3 + j] + (double)br[i * 3 + j];
  for (int i = 0; i < 3; ++i) {
    double nn = sqrt(m[i][0] * m[i][0] + m[i][1] * m[i][1] + m[i][2] * m[i][2]);
    if (nn < 1e-12) nn = 1e-12;
    m[i][0] /= nn; m[i][1] /= nn; m[i][2] /= nn;
  }
  double Km[3][3];
  for (int a = 0; a < 3; ++a)
    for (int b = 0; b < 3; ++b) {
      double s = 0;
      for (int i = 0; i < 3; ++i) s += m[i][a] * m[i][b];
      Km[a][b] = s;
    }
  double V[3][3] = {{1, 0, 0}, {0, 1, 0}, {0, 0, 1}};
  const int PQ[3][2] = {{0, 1}, {0, 2}, {1, 2}};
  for (int sweep = 0; sweep < 20; ++sweep) {
    for (int e = 0; e < 3; ++e) {
      int p = PQ[e][0], qq = PQ[e][1];
      double apq = Km[p][qq];
      if (apq == 0.0) continue;
      double tau = (Km[qq][qq] - Km[p][p]) / (2.0 * apq);
      double tt = (tau >= 0.0 ? 1.0 : -1.0) / (fabs(tau) + sqrt(1.0 + tau * tau));
      double cc = 1.0 / sqrt(1.0 + tt * tt), ss = tt * cc;
      for (int k = 0; k < 3; ++k) { double a1 = Km[p][k], a2 = Km[qq][k]; Km[p][k] = cc * a1 - ss * a2; Km[qq][k] = ss * a1 + cc * a2; }
      for (int k = 0; k < 3; ++k) { double a1 = Km[k][p], a2 = Km[k][qq]; Km[k][p] = cc * a1 - ss * a2; Km[k][qq] = ss * a1 + cc * a2; }
      for (int k = 0; k < 3; ++k) { double a1 = V[k][p], a2 = V[k][qq]; V[k][p] = cc * a1 - ss * a2; V[k][qq] = ss * a1 + cc * a2; }
    }
  }
  double lam[3] = {Km[0][0], Km[1][1], Km[2][2]};
  int o0 = 0, o1 = 1, o2 = 2; double detV = 1.0;
  if (lam[o0] < lam[o1]) { int t = o0; o0 = o1; o1 = t; detV = -detV; }
  if (lam[o1] < lam[o2]) { int t = o1; o1 = o2; o2 = t; detV = -detV; }
  if (lam[o0] < lam[o1]) { int t = o0; o0 = o1; o1 = t; detV = -detV; }
  double v0[3] = {V[0][o0], V[1][o0], V[2][o0]};
  double v1[3] = {V[0][o1], V[1][o1], V[2][o1]};
  double v2[3] = {V[0][o2], V[1][o2], V[2][o2]};
  double u0[3], u1[3];
  for (int i = 0; i < 3; ++i) u0[i] = m[i][0] * v0[0] + m[i][1] * v0[1] + m[i][2] * v0[2];
  double n0 = sqrt(u0[0] * u0[0] + u0[1] * u0[1] + u0[2] * u0[2]); if (n0 < 1e-30) n0 = 1e-30;
  for (int i = 0; i < 3; ++i) u0[i] /= n0;
  for (int i = 0; i < 3; ++i) u1[i] = m[i][0] * v1[0] + m[i][1] * v1[1] + m[i][2] * v1[2];
  double d01 = u0[0] * u1[0] + u0[1] * u1[1] + u0[2] * u1[2];
  for (int i = 0; i < 3; ++i) u1[i] -= d01 * u0[i];
  double n1 = sqrt(u1[0] * u1[0] + u1[1] * u1[1] + u1[2] * u1[2]); if (n1 < 1e-30) n1 = 1e-30;
  for (int i = 0; i < 3; ++i) u1[i] /= n1;
  double u2[3] = {u0[1] * u1[2] - u0[2] * u1[1],
                  u0[2] * u1[0] - u0[0] * u1[2],
                  u0[0] * u1[1] - u0[1] * u1[0]};
  float* o = out + (long)row * 16;
  for (int i = 0; i < 3; ++i) {
    for (int j = 0; j < 3; ++j)
      o[i * 4 + j] = (float)(u0[i] * v0[j] + u1[i] * v1[j] + detV * u2[i] * v2[j]);
    o[i * 4 + 3] = (float)t3[i];
  }
  o[12] = 0.f; o[13] = 0.f; o[14] = 0.f; o[15] = 1.f;
}

// ---------------------------------------------------------------------------
extern "C" void kernel_launch(void* const* d_in, const int* in_sizes, int n_in,
                              void* d_out, int out_size, void* d_ws, size_t ws_size,
                              hipStream_t stream) {
  (void)in_sizes; (void)n_in; (void)out_size; (void)ws_size;
  const float* feat   = (const float*)d_in[0];
  const float* W_res  = (const float*)d_in[5];
  const float* b_res  = (const float*)d_in[6];
  const float* W_cur1 = (const float*)d_in[7];
  const float* b_cur1 = (const float*)d_in[8];
  const float* W_cur2 = (const float*)d_in[9];
  const float* b_cur2 = (const float*)d_in[10];
  const float* W_tp1  = (const float*)d_in[11];
  const float* b_tp1  = (const float*)d_in[12];
  const float* W_tp2  = (const float*)d_in[13];
  const float* b_tp2  = (const float*)d_in[14];
  const float* W_fut1 = (const float*)d_in[15];
  const float* b_fut1 = (const float*)d_in[16];
  const float* W_fut2 = (const float*)d_in[17];
  const float* b_fut2 = (const float*)d_in[18];
  const float* W_m1   = (const float*)d_in[19];
  const float* b_m1   = (const float*)d_in[20];
  const float* W_m2   = (const float*)d_in[21];
  const float* b_m2   = (const float*)d_in[22];
  const float* W_t    = (const float*)d_in[23];
  const float* b_t    = (const float*)d_in[24];
  const float* W_r    = (const float*)d_in[25];
  const float* b_r    = (const float*)d_in[26];

  char* ws = (char*)d_ws;
  const size_t SZ_BIG = (size_t)R_PAD * DDIM * 2;  // 134,610,944 B
  u16* A  = (u16*)(ws);                  // feat (bf16, padded) - updated in place
  u16* Wp = (u16*)(ws + SZ_BIG);         // 6x packed fragment-linear weights
  char* tail = ws + SZ_BIG + (size_t)6 * 262144 * 2;
  float* pooled = (float*)(tail);            // [96][512]
  float* gctx   = pooled + 96 * 512;         // [32][512]
  float* tmp    = gctx + 32 * 512;           // [192][512] scratch
  float* tfb    = tmp + 192 * 512;           // [32][1536] == [96][512]
  float* allf   = tfb + 32 * 1536;           // [192][512]
  float* h2     = allf + 192 * 512;          // [192][512]
  float* outp   = (float*)d_out;

  convert_feat_k<<<65728, 256, 0, stream>>>(feat, A);
  pack_w_k<<<6144, 256, 0, stream>>>(W_res, Wp);

  // Fused ResConvBlocks (2054 x 64-row tiles each)
  fused_res_k<<<2054, 256, 0, stream>>>(A, Wp,                 b_res);
  fused_res_k<<<2054, 256, 0, stream>>>(A, Wp + 3L * 262144,   b_res + 3 * 512);

  zero_k<<<(96 * 512 + 255) / 256, 256, 0, stream>>>(pooled, 96 * 512);
  pool_k<<<dim3(96, 8), 512, 0, stream>>>(A, pooled);
  gctx_k<<<(32 * 512 + 255) / 256, 256, 0, stream>>>(pooled, gctx);

  lin_k<true ><<<dim3(2, 96),  256, 0, stream>>>(pooled, W_cur1, b_cur1, tmp, 512, 512);
  lin_k<false><<<dim3(2, 96),  256, 0, stream>>>(tmp, W_cur2, b_cur2, allf, 512, 512);
  lin_k<true ><<<dim3(2, 32),  256, 0, stream>>>(gctx, W_tp1, b_tp1, tmp, 512, 512);
  lin_k<false><<<dim3(6, 32),  256, 0, stream>>>(tmp, W_tp2, b_tp2, tfb, 512, 1536);
  lin_k<true ><<<dim3(2, 96),  256, 0, stream>>>(tfb, W_fut1, b_fut1, tmp, 512, 512);
  lin_k<false><<<dim3(2, 96),  256, 0, stream>>>(tmp, W_fut2, b_fut2, allf + 96 * 512, 512, 512);
  lin_k<true ><<<dim3(2, 192), 256, 0, stream>>>(allf, W_m1, b_m1, tmp, 512, 512);
  lin_k<true ><<<dim3(2, 192), 256, 0, stream>>>(tmp, W_m2, b_m2, h2, 512, 512);

  pose_k<<<192, 64, 0, stream>>>(h2, W_t, b_t, W_r, b_r, outp);
}